// Round 3
// baseline (201.739 us; speedup 1.0000x reference)
//
#include <hip/hip_runtime.h>
#include <math.h>

#define NB 32
#define LL 512
#define HH 1024
#define H2 512
#define DA 64

typedef unsigned int u32;
typedef unsigned short u16;
typedef __bf16 bf16x8 __attribute__((ext_vector_type(8)));
typedef float f32x4 __attribute__((ext_vector_type(4)));

__device__ __forceinline__ u16 f2bu(float f) {          // fp32 -> bf16 bits, RNE
    u32 u = __builtin_bit_cast(u32, f);
    u = (u + 0x7fff + ((u >> 16) & 1)) >> 16;
    return (u16)u;
}

__device__ __forceinline__ float b2f(u16 u) {           // bf16 bits -> fp32
    u32 v = (u32)u << 16;
    return __builtin_bit_cast(float, v);
}

__device__ __forceinline__ void async_cp16(const void* g, void* l) {
    __builtin_amdgcn_global_load_lds(
        (const __attribute__((address_space(1))) u32*)g,
        (__attribute__((address_space(3))) u32*)l, 16, 0, 0);
}

// ========== prep: bf16 weight materialization (weights only, reverted) ==========
__global__ void prep_kernel(const float* __restrict__ wv,
                            const float* __restrict__ kqvw,
                            const float* __restrict__ projw,
                            u16* __restrict__ wt, u16* __restrict__ kqvwT,
                            u16* __restrict__ projwT) {
    int e = blockIdx.x * 256 + threadIdx.x;
    if (e < 262144) {
        int m = e >> 9, l = e & 511;
        wt[e] = f2bu(wv[511 + m - l]);
    } else if (e < 262144 + 98304) {
        int i = e - 262144;
        int n = i >> 9, k = i & 511;
        kqvwT[i] = f2bu(kqvw[(size_t)k * 192 + n]);
    } else {
        int i = e - 360448;
        int c = i >> 6, d = i & 63;
        projwT[i] = f2bu(projw[(size_t)d * 512 + c]);
    }
}

// ========== front: pure LN+transpose stream (stats in-reg, 1 barrier) ==========
// 512 blocks x 512 threads (16 waves/CU). Thread (r = t>>4, cl = t&15) loads 8
// float4 of row r (contiguous 256B per 16-lane group), reduces stats over the
// 16-lane row group, affines in-reg, writes swizzled transpose to LDS; phase B
// dumps vnT rows as full 64B lines.
__global__ __launch_bounds__(512, 4)
void front_kernel(const float* __restrict__ x,
                  const float* __restrict__ gamma, const float* __restrict__ beta,
                  u16* __restrict__ vnT) {
    __shared__ u16 T[512 * 36];                 // 36864 B, pad 36 (+swizzle)
    int blk = blockIdx.x, t = threadIdx.x;
    int b = blk >> 4, l0 = (blk & 15) * 32;
    int r = t >> 4, cl = t & 15;
    int rs = r ^ ((cl & 3) << 3);               // write swizzle (2-way max)
    const float* xr = x + ((size_t)(b * LL + l0 + r)) * HH + H2;

    float4 v[8];
#pragma unroll
    for (int i = 0; i < 8; ++i) v[i] = *(const float4*)(xr + i * 64 + cl * 4);
    float s1 = 0.0f, s2 = 0.0f;
#pragma unroll
    for (int i = 0; i < 8; ++i) {
        s1 += v[i].x + v[i].y + v[i].z + v[i].w;
        s2 += v[i].x * v[i].x + v[i].y * v[i].y + v[i].z * v[i].z + v[i].w * v[i].w;
    }
    s1 += __shfl_xor(s1, 1); s2 += __shfl_xor(s2, 1);
    s1 += __shfl_xor(s1, 2); s2 += __shfl_xor(s2, 2);
    s1 += __shfl_xor(s1, 4); s2 += __shfl_xor(s2, 4);
    s1 += __shfl_xor(s1, 8); s2 += __shfl_xor(s2, 8);
    float mu = s1 * (1.0f / H2);
    float rstd = rsqrtf(s2 * (1.0f / H2) - mu * mu + 1e-5f);

#pragma unroll
    for (int hh = 0; hh < 2; ++hh) {            // two halves: caps VGPR pressure
        float4 g[4], be[4];
#pragma unroll
        for (int i = 0; i < 4; ++i) {
            g[i]  = *(const float4*)(gamma + (hh * 4 + i) * 64 + cl * 4);
            be[i] = *(const float4*)(beta  + (hh * 4 + i) * 64 + cl * 4);
        }
#pragma unroll
        for (int i = 0; i < 4; ++i) {
            int ii = hh * 4 + i;
            int c = ii * 64 + cl * 4;
            float4 vv = v[ii];
            T[(c + 0) * 36 + rs] = f2bu((vv.x - mu) * rstd * g[i].x + be[i].x);
            T[(c + 1) * 36 + rs] = f2bu((vv.y - mu) * rstd * g[i].y + be[i].y);
            T[(c + 2) * 36 + rs] = f2bu((vv.z - mu) * rstd * g[i].z + be[i].z);
            T[(c + 3) * 36 + rs] = f2bu((vv.w - mu) * rstd * g[i].w + be[i].w);
        }
    }
    __syncthreads();

    // phase B: thread t = c; gather de-swizzled 64B row-window, one full line out
    int c = t;
    int swzB = ((c >> 2) & 3) << 3;
    const u16* Tp = T + c * 36;
    ushort4 o[8];
#pragma unroll
    for (int h = 0; h < 8; ++h)
        o[h] = *(const ushort4*)(Tp + ((h << 2) ^ swzB));
    u16* dst = vnT + ((size_t)(b * H2 + c)) * LL + l0;
#pragma unroll
    for (int h = 0; h < 4; ++h) {
        union { ushort4 u2[2]; uint4 q; } pk;
        pk.u2[0] = o[2 * h]; pk.u2[1] = o[2 * h + 1];
        ((uint4*)dst)[h] = pk.q;
    }
}

// ========== kqv: skinny GEMM, barrier-free K-loop, reg double-buffer ==========
// 1024 blocks x 4 waves; wave = 16 rows x 48 N x K=512. A from x (L3-hot),
// B-frags from L2-resident kqvwT. LDS only for the coalesced epilogue.
__global__ __launch_bounds__(256, 4)
void kqv_kernel(const float* __restrict__ x,
                const u16* __restrict__ kqvwT, const float* __restrict__ kqvb,
                u16* __restrict__ qb, u16* __restrict__ kb, u16* __restrict__ vT) {
    __shared__ u16 Ks[16 * 64];                 // 2 KB
    __shared__ u16 Qs[16 * 64];                 // 2 KB
    __shared__ u16 Vs[64 * 40];                 // 5 KB (pad 40 for 8B-aligned reads)
    int blk = blockIdx.x, t = threadIdx.x;
    int R0 = blk * 16;                          // global row base (b*512 + l0)
    int b = R0 >> 9, l0 = R0 & 511;
    int lane = t & 63, wid = t >> 6;
    int l15 = lane & 15, q16 = lane >> 4, q8 = q16 * 8;
    int n0 = wid * 48;
    const float* xa = x + ((size_t)(R0 + l15)) * HH + H2;
    const u16* Bb = kqvwT + (size_t)(n0 + l15) * 512;

    f32x4 acc[3] = {};
    float4 a0 = *(const float4*)(xa + q8);
    float4 a1 = *(const float4*)(xa + q8 + 4);
    bf16x8 b0 = *(const bf16x8*)(Bb + 0 * 8192 + q8);
    bf16x8 b1 = *(const bf16x8*)(Bb + 1 * 8192 + q8);
    bf16x8 b2 = *(const bf16x8*)(Bb + 2 * 8192 + q8);
#pragma unroll
    for (int it = 0; it < 16; ++it) {
        float4 na0, na1; bf16x8 nb0, nb1, nb2;
        if (it < 15) {                          // prefetch next K-step into regs
            int ko = (it + 1) * 32 + q8;
            na0 = *(const float4*)(xa + ko);
            na1 = *(const float4*)(xa + ko + 4);
            nb0 = *(const bf16x8*)(Bb + 0 * 8192 + ko);
            nb1 = *(const bf16x8*)(Bb + 1 * 8192 + ko);
            nb2 = *(const bf16x8*)(Bb + 2 * 8192 + ko);
        }
        bf16x8 a;
        a[0] = __builtin_bit_cast(__bf16, f2bu(a0.x));
        a[1] = __builtin_bit_cast(__bf16, f2bu(a0.y));
        a[2] = __builtin_bit_cast(__bf16, f2bu(a0.z));
        a[3] = __builtin_bit_cast(__bf16, f2bu(a0.w));
        a[4] = __builtin_bit_cast(__bf16, f2bu(a1.x));
        a[5] = __builtin_bit_cast(__bf16, f2bu(a1.y));
        a[6] = __builtin_bit_cast(__bf16, f2bu(a1.z));
        a[7] = __builtin_bit_cast(__bf16, f2bu(a1.w));
        acc[0] = __builtin_amdgcn_mfma_f32_16x16x32_bf16(a, b0, acc[0], 0, 0, 0);
        acc[1] = __builtin_amdgcn_mfma_f32_16x16x32_bf16(a, b1, acc[1], 0, 0, 0);
        acc[2] = __builtin_amdgcn_mfma_f32_16x16x32_bf16(a, b2, acc[2], 0, 0, 0);
        a0 = na0; a1 = na1; b0 = nb0; b1 = nb1; b2 = nb2;
    }

    // epilogue: +bias, stage k/q/vT tiles in LDS, then coalesced dumps
    int rq = q16 * 4;
#pragma unroll
    for (int j = 0; j < 3; ++j) {
        int n = n0 + j * 16 + l15;
        float bias = kqvb[n];
#pragma unroll
        for (int rr = 0; rr < 4; ++rr) {
            int m = rq + rr;
            u16 hv = f2bu(acc[j][rr] + bias);
            if (n < 64)       Ks[m * 64 + n] = hv;
            else if (n < 128) Qs[m * 64 + (n - 64)] = hv;
            else              Vs[(n - 128) * 40 + m] = hv;
        }
    }
    __syncthreads();
    {
        size_t base = (size_t)R0 * 64;
        *(ushort4*)(kb + base + t * 4) = *(const ushort4*)(Ks + t * 4);
        *(ushort4*)(qb + base + t * 4) = *(const ushort4*)(Qs + t * 4);
        int d = t >> 2, ls = (t & 3) * 4;
        *(ushort4*)(vT + ((size_t)(b * 64 + d)) * 512 + l0 + ls) =
            *(const ushort4*)(Vs + d * 40 + ls);
    }
}

// ========== MFMA flash attention, split-K across 4 waves (unchanged) ==========
#define VLD 136
__global__ __launch_bounds__(256, 4)
void attn_kernel(const u16* __restrict__ qb, const u16* __restrict__ kb,
                 const u16* __restrict__ vT, u16* __restrict__ head) {
    __shared__ u16 Ps[4 * 16 * VLD];
    __shared__ float Osh[4][16 * 65];
    __shared__ float Msh[4][16], Lsh[4][16];
    int b = blockIdx.y, q0 = blockIdx.x * 16;
    int t = threadIdx.x, lane = t & 63, w = t >> 6;
    int l15 = lane & 15, q16 = lane >> 4, q8 = q16 * 8;
    int kc = w * 128;
    const u16* qg = qb + (size_t)b * LL * DA;
    const u16* kg = kb + (size_t)b * LL * DA;
    const u16* vg = vT + (size_t)b * DA * LL;

    bf16x8 aq[2];
#pragma unroll
    for (int s = 0; s < 2; ++s)
        aq[s] = *(const bf16x8*)(qg + (size_t)(q0 + l15) * DA + s * 32 + q8);

    f32x4 sc[8] = {};
#pragma unroll
    for (int j = 0; j < 8; ++j) {
#pragma unroll
        for (int s = 0; s < 2; ++s) {
            bf16x8 bk = *(const bf16x8*)(kg + (size_t)(kc + j * 16 + l15) * DA + s * 32 + q8);
            sc[j] = __builtin_amdgcn_mfma_f32_16x16x32_bf16(aq[s], bk, sc[j], 0, 0, 0);
        }
    }
    float mx[4], sm[4];
#pragma unroll
    for (int j = 0; j < 8; ++j)
#pragma unroll
        for (int rr = 0; rr < 4; ++rr) sc[j][rr] *= 0.125f;
#pragma unroll
    for (int rr = 0; rr < 4; ++rr) {
        float m0 = sc[0][rr];
#pragma unroll
        for (int j = 1; j < 8; ++j) m0 = fmaxf(m0, sc[j][rr]);
        m0 = fmaxf(m0, __shfl_xor(m0, 1));
        m0 = fmaxf(m0, __shfl_xor(m0, 2));
        m0 = fmaxf(m0, __shfl_xor(m0, 4));
        m0 = fmaxf(m0, __shfl_xor(m0, 8));
        mx[rr] = m0;
    }
#pragma unroll
    for (int j = 0; j < 8; ++j)
#pragma unroll
        for (int rr = 0; rr < 4; ++rr) sc[j][rr] = __expf(sc[j][rr] - mx[rr]);
#pragma unroll
    for (int rr = 0; rr < 4; ++rr) {
        float s0 = sc[0][rr];
#pragma unroll
        for (int j = 1; j < 8; ++j) s0 += sc[j][rr];
        s0 += __shfl_xor(s0, 1);
        s0 += __shfl_xor(s0, 2);
        s0 += __shfl_xor(s0, 4);
        s0 += __shfl_xor(s0, 8);
        sm[rr] = s0;
    }
    u16* Pw = Ps + w * 16 * VLD;
#pragma unroll
    for (int j = 0; j < 8; ++j)
#pragma unroll
        for (int rr = 0; rr < 4; ++rr)
            Pw[(q16 * 4 + rr) * VLD + j * 16 + l15] = f2bu(sc[j][rr]);
    f32x4 o[4] = {};
#pragma unroll
    for (int kt = 0; kt < 4; ++kt) {
        bf16x8 ap = *(const bf16x8*)(Pw + l15 * VLD + kt * 32 + q8);
#pragma unroll
        for (int j = 0; j < 4; ++j) {
            bf16x8 bv = *(const bf16x8*)(vg + (size_t)(j * 16 + l15) * LL + kc + kt * 32 + q8);
            o[j] = __builtin_amdgcn_mfma_f32_16x16x32_bf16(ap, bv, o[j], 0, 0, 0);
        }
    }
#pragma unroll
    for (int j = 0; j < 4; ++j)
#pragma unroll
        for (int rr = 0; rr < 4; ++rr)
            Osh[w][(q16 * 4 + rr) * 65 + j * 16 + l15] = o[j][rr];
    if (l15 == 0) {
#pragma unroll
        for (int rr = 0; rr < 4; ++rr) {
            Msh[w][q16 * 4 + rr] = mx[rr];
            Lsh[w][q16 * 4 + rr] = sm[rr];
        }
    }
    __syncthreads();
    int qq = t >> 4, dg = (t & 15) * 4;
    float m0 = Msh[0][qq], m1 = Msh[1][qq], m2 = Msh[2][qq], m3 = Msh[3][qq];
    float ms = fmaxf(fmaxf(m0, m1), fmaxf(m2, m3));
    float f0 = __expf(m0 - ms), f1 = __expf(m1 - ms), f2 = __expf(m2 - ms), f3 = __expf(m3 - ms);
    float lst = Lsh[0][qq] * f0 + Lsh[1][qq] * f1 + Lsh[2][qq] * f2 + Lsh[3][qq] * f3;
    float inv = 1.0f / lst;
    ushort4 res;
    u16* rp = (u16*)&res;
#pragma unroll
    for (int i = 0; i < 4; ++i) {
        int idx = qq * 65 + dg + i;
        float a = Osh[0][idx] * f0 + Osh[1][idx] * f1 + Osh[2][idx] * f2 + Osh[3][idx] * f3;
        rp[i] = f2bu(a * inv);
    }
    *(ushort4*)(head + (size_t)(b * LL + q0 + qq) * DA + dg) = res;
}

// ========== fused Toeplitz GEMM + proj + bias + gate, double-buffered pipeline ==========
__device__ __forceinline__ void mfma_tile64(const u16* As, const u16* Bs,
                                            f32x4 acc[4][4], int wm, int wn,
                                            int l15, int q16) {
    int s7 = l15 & 7;
#pragma unroll
    for (int kk = 0; kk < 2; ++kk) {
        int j0 = kk * 4 + q16;
        bf16x8 a[4], bv[4];
#pragma unroll
        for (int i = 0; i < 4; ++i) {
            int row = wm + i * 16 + l15;
            a[i] = *(const bf16x8*)(As + (row * 8 + (j0 ^ s7)) * 8);
        }
#pragma unroll
        for (int j = 0; j < 4; ++j) {
            int row = wn + j * 16 + l15;
            bv[j] = *(const bf16x8*)(Bs + (row * 8 + (j0 ^ s7)) * 8);
        }
#pragma unroll
        for (int i = 0; i < 4; ++i)
#pragma unroll
            for (int j = 0; j < 4; ++j)
                acc[i][j] = __builtin_amdgcn_mfma_f32_16x16x32_bf16(a[i], bv[j], acc[i][j], 0, 0, 0);
    }
}

__device__ __forceinline__ void stage_pair(const u16* A, const u16* B, int ldk,
                                           int koff, u16* Ad, u16* Bd, int t) {
#pragma unroll
    for (int s = 0; s < 4; ++s) {
        int ci = t + s * 256;
        int grow = ci >> 3, gcol = ((ci & 7) ^ (grow & 7)) << 3;
        async_cp16(A + (size_t)grow * ldk + koff + gcol, Ad + ci * 8);
        async_cp16(B + (size_t)grow * ldk + koff + gcol, Bd + ci * 8);
    }
}

__global__ __launch_bounds__(256, 2)
void mix_kernel(const u16* __restrict__ wt,      // [512 m][512 l]
                const u16* __restrict__ vnT,     // [B][512 c][512 l]
                const u16* __restrict__ headb,   // [B][512 m][64 d]
                const u16* __restrict__ projwT,  // [512 c][64 d]
                const float* __restrict__ x,
                const float* __restrict__ tbias,
                const float* __restrict__ projb,
                float* __restrict__ out) {
    __shared__ u16 As[2][128 * 64];              // 2 x 16 KiB
    __shared__ u16 Bs[2][128 * 64];              // 2 x 16 KiB  (total 64 KiB, 2 blk/CU)
    int lid = blockIdx.x;
    int p8 = lid & 7, rest = lid >> 3;
    int mi = rest & 3, pair = (rest >> 2) * 8 + p8;   // pair in [0,128)
    int b = pair >> 2, m0 = mi * 128, c0 = (pair & 3) * 128;
    int t = threadIdx.x, lane = t & 63, wid = t >> 6;
    int wm = (wid >> 1) * 64, wn = (wid & 1) * 64;
    int l15 = lane & 15, q16 = lane >> 4;
    f32x4 acc[4][4] = {};
    const u16* Ag = wt + (size_t)m0 * 512;
    const u16* Bg = vnT + ((size_t)b * H2 + c0) * 512;
    const u16* Hg = headb + ((size_t)b * LL + m0) * DA;
    const u16* Pg = projwT + (size_t)c0 * DA;

    // prologue: stage tile 0 (Toeplitz k0=0) into buf 0
    stage_pair(Ag, Bg, 512, 0, As[0], Bs[0], t);
    __syncthreads();                             // drains DMA

    // 9-tile pipeline: 8 Toeplitz K-slabs + proj as tile 8; stage-next ∥ MFMA-current
    for (int it = 0; it < 9; ++it) {
        int nx = it + 1;
        if (nx < 8)
            stage_pair(Ag, Bg, 512, nx * 64, As[nx & 1], Bs[nx & 1], t);
        else if (nx == 8)
            stage_pair(Hg, Pg, 64, 0, As[0], Bs[0], t);
        mfma_tile64(As[it & 1], Bs[it & 1], acc, wm, wn, l15, q16);
        __syncthreads();                         // next-buf ready; cur buf released
    }

    int rq = q16 * 4;
#pragma unroll
    for (int i = 0; i < 4; ++i) {
#pragma unroll
        for (int rr = 0; rr < 4; ++rr) {
            int m = m0 + wm + i * 16 + rq + rr;
            float tb = tbias[m];
            const float* xrow = x + ((size_t)b * LL + m) * HH;
            float* orow = out + ((size_t)b * LL + m) * H2;
#pragma unroll
            for (int j = 0; j < 4; ++j) {
                int c = c0 + wn + j * 16 + l15;
                float val = acc[i][j][rr] + tb + projb[c];
                orow[c] = xrow[c] * val;
            }
        }
    }
}

extern "C" void kernel_launch(void* const* d_in, const int* in_sizes, int n_in,
                              void* d_out, int out_size, void* d_ws, size_t ws_size,
                              hipStream_t stream) {
    (void)in_sizes; (void)n_in; (void)out_size; (void)ws_size;
    const float* x     = (const float*)d_in[0];
    const float* gamma = (const float*)d_in[1];
    const float* beta  = (const float*)d_in[2];
    const float* wv    = (const float*)d_in[3];
    const float* tb    = (const float*)d_in[4];
    const float* kqvw  = (const float*)d_in[5];
    const float* kqvb  = (const float*)d_in[6];
    const float* projw = (const float*)d_in[7];
    const float* projb = (const float*)d_in[8];
    float* out = (float*)d_out;

    u16* vnT_bf  = (u16*)d_ws;                          // 16 MB
    u16* qb      = vnT_bf + (size_t)NB * LL * H2;       // 2 MB
    u16* kb      = qb + (size_t)NB * LL * DA;           // 2 MB
    u16* vTb     = kb + (size_t)NB * LL * DA;           // 2 MB
    u16* head_bf = vTb + (size_t)NB * LL * DA;          // 2 MB
    u16* wt_bf   = head_bf + (size_t)NB * LL * DA;      // 512 KB
    u16* kqvwT   = wt_bf + 512 * 512;                   // 192 KB
    u16* projwT  = kqvwT + 192 * 512;                   // 64 KB

    prep_kernel <<<1536, 256, 0, stream>>>(wv, kqvw, projw, wt_bf, kqvwT, projwT);
    front_kernel<<<512, 512, 0, stream>>>(x, gamma, beta, vnT_bf);
    kqv_kernel  <<<1024, 256, 0, stream>>>(x, kqvwT, kqvb, qb, kb, vTb);
    attn_kernel <<<dim3(32, NB), 256, 0, stream>>>(qb, kb, vTb, head_bf);
    mix_kernel  <<<512, 256, 0, stream>>>(wt_bf, vnT_bf, head_bf, projwT,
                                          x, tb, projb, out);
}

// Round 4
// 181.392 us; speedup vs baseline: 1.1122x; 1.1122x over previous
//
#include <hip/hip_runtime.h>
#include <math.h>

#define NB 32
#define LL 512
#define HH 1024
#define H2 512
#define DA 64

typedef unsigned int u32;
typedef unsigned short u16;
typedef __bf16 bf16x8 __attribute__((ext_vector_type(8)));
typedef float f32x4 __attribute__((ext_vector_type(4)));

__device__ __forceinline__ u16 f2bu(float f) {          // fp32 -> bf16 bits, RNE
    u32 u = __builtin_bit_cast(u32, f);
    u = (u + 0x7fff + ((u >> 16) & 1)) >> 16;
    return (u16)u;
}

__device__ __forceinline__ float b2f(u16 u) {           // bf16 bits -> fp32
    u32 v = (u32)u << 16;
    return __builtin_bit_cast(float, v);
}

__device__ __forceinline__ void async_cp16(const void* g, void* l) {
    __builtin_amdgcn_global_load_lds(
        (const __attribute__((address_space(1))) u32*)g,
        (__attribute__((address_space(3))) u32*)l, 16, 0, 0);
}

// ========== prep: bf16 weight materialization (unchanged) ==========
__global__ void prep_kernel(const float* __restrict__ wv,
                            const float* __restrict__ kqvw,
                            const float* __restrict__ projw,
                            u16* __restrict__ wt, u16* __restrict__ kqvwT,
                            u16* __restrict__ projwT) {
    int e = blockIdx.x * 256 + threadIdx.x;
    if (e < 262144) {
        int m = e >> 9, l = e & 511;
        wt[e] = f2bu(wv[511 + m - l]);
    } else if (e < 262144 + 98304) {
        int i = e - 262144;
        int n = i >> 9, k = i & 511;
        kqvwT[i] = f2bu(kqvw[(size_t)k * 192 + n]);
    } else {
        int i = e - 360448;
        int c = i >> 6, d = i & 63;
        projwT[i] = f2bu(projw[(size_t)d * 512 + c]);
    }
}

// ========== front: pure LN+transpose stream (unchanged from R3) ==========
__global__ __launch_bounds__(512, 4)
void front_kernel(const float* __restrict__ x,
                  const float* __restrict__ gamma, const float* __restrict__ beta,
                  u16* __restrict__ vnT) {
    __shared__ u16 T[512 * 36];                 // 36864 B, pad 36 (+swizzle)
    int blk = blockIdx.x, t = threadIdx.x;
    int b = blk >> 4, l0 = (blk & 15) * 32;
    int r = t >> 4, cl = t & 15;
    int rs = r ^ ((cl & 3) << 3);               // write swizzle (2-way max)
    const float* xr = x + ((size_t)(b * LL + l0 + r)) * HH + H2;

    float4 v[8];
#pragma unroll
    for (int i = 0; i < 8; ++i) v[i] = *(const float4*)(xr + i * 64 + cl * 4);
    float s1 = 0.0f, s2 = 0.0f;
#pragma unroll
    for (int i = 0; i < 8; ++i) {
        s1 += v[i].x + v[i].y + v[i].z + v[i].w;
        s2 += v[i].x * v[i].x + v[i].y * v[i].y + v[i].z * v[i].z + v[i].w * v[i].w;
    }
    s1 += __shfl_xor(s1, 1); s2 += __shfl_xor(s2, 1);
    s1 += __shfl_xor(s1, 2); s2 += __shfl_xor(s2, 2);
    s1 += __shfl_xor(s1, 4); s2 += __shfl_xor(s2, 4);
    s1 += __shfl_xor(s1, 8); s2 += __shfl_xor(s2, 8);
    float mu = s1 * (1.0f / H2);
    float rstd = rsqrtf(s2 * (1.0f / H2) - mu * mu + 1e-5f);

#pragma unroll
    for (int hh = 0; hh < 2; ++hh) {            // two halves: caps VGPR pressure
        float4 g[4], be[4];
#pragma unroll
        for (int i = 0; i < 4; ++i) {
            g[i]  = *(const float4*)(gamma + (hh * 4 + i) * 64 + cl * 4);
            be[i] = *(const float4*)(beta  + (hh * 4 + i) * 64 + cl * 4);
        }
#pragma unroll
        for (int i = 0; i < 4; ++i) {
            int ii = hh * 4 + i;
            int c = ii * 64 + cl * 4;
            float4 vv = v[ii];
            T[(c + 0) * 36 + rs] = f2bu((vv.x - mu) * rstd * g[i].x + be[i].x);
            T[(c + 1) * 36 + rs] = f2bu((vv.y - mu) * rstd * g[i].y + be[i].y);
            T[(c + 2) * 36 + rs] = f2bu((vv.z - mu) * rstd * g[i].z + be[i].z);
            T[(c + 3) * 36 + rs] = f2bu((vv.w - mu) * rstd * g[i].w + be[i].w);
        }
    }
    __syncthreads();

    // phase B: thread t = c; gather de-swizzled 64B row-window, one full line out
    int c = t;
    int swzB = ((c >> 2) & 3) << 3;
    const u16* Tp = T + c * 36;
    ushort4 o[8];
#pragma unroll
    for (int h = 0; h < 8; ++h)
        o[h] = *(const ushort4*)(Tp + ((h << 2) ^ swzB));
    u16* dst = vnT + ((size_t)(b * H2 + c)) * LL + l0;
#pragma unroll
    for (int h = 0; h < 4; ++h) {
        union { ushort4 u2[2]; uint4 q; } pk;
        pk.u2[0] = o[2 * h]; pk.u2[1] = o[2 * h + 1];
        ((uint4*)dst)[h] = pk.q;
    }
}

// ========== kqv: tiled GEMM, BM=64, BK=64, dbuf LDS, 256 blocks ==========
// B (192x512, L2-resident) staged per K-step via swizzled global_load_lds and
// shared by all 4 waves: aggregate B traffic 256x192KB = 49MB (was 196MB).
// A staged from x with T14 async split: issue loads -> MFMA current -> cvt+write.
__global__ __launch_bounds__(256, 2)
void kqv_kernel(const float* __restrict__ x,
                const u16* __restrict__ kqvwT, const float* __restrict__ kqvb,
                u16* __restrict__ qb, u16* __restrict__ kb, u16* __restrict__ vT) {
    __shared__ u16 As_[2][64 * 72];             // 2 x 9216 B (pad 72: 2-way max)
    __shared__ u16 Bs_[2][192 * 64];            // 2 x 24576 B (swizzled granules)
    int blk = blockIdx.x, t = threadIdx.x;
    int R0 = blk * 64;                          // global row base (b*512 + l0)
    int b = R0 >> 9, l0 = R0 & 511;
    int lane = t & 63, wid = t >> 6;
    int l15 = lane & 15, q16 = lane >> 4, q8 = q16 * 8;
    int wm = (wid & 1) * 32, wn = (wid >> 1) * 96;
    const float* xg = x + (size_t)R0 * HH + H2;

    // A-stage mapping: p-th chunk, flat = t + p*256; row = flat>>4, f4 = flat&15
    int arow[4], af4[4];
#pragma unroll
    for (int p = 0; p < 4; ++p) {
        int flat = t + p * 256;
        arow[p] = flat >> 4; af4[p] = flat & 15;
    }

    f32x4 acc[2][6] = {};
    float4 av[4];

    // ---- prologue: stage k0=0 into buf 0 ----
#pragma unroll
    for (int p = 0; p < 4; ++p)
        av[p] = *(const float4*)(xg + (size_t)arow[p] * HH + af4[p] * 4);
#pragma unroll
    for (int s = 0; s < 6; ++s) {
        int ci = t + s * 256;
        int grow = ci >> 3, gcol = ((ci & 7) ^ (grow & 7)) << 3;
        async_cp16(kqvwT + (size_t)grow * 512 + gcol, &Bs_[0][ci * 8]);
    }
#pragma unroll
    for (int p = 0; p < 4; ++p) {
        ushort4 pk;
        pk.x = f2bu(av[p].x); pk.y = f2bu(av[p].y);
        pk.z = f2bu(av[p].z); pk.w = f2bu(av[p].w);
        *(ushort4*)(&As_[0][arow[p] * 72 + af4[p] * 4]) = pk;
    }
    __syncthreads();

    // ---- 8-step pipeline: issue next loads -> MFMA current -> cvt+write next ----
    for (int it = 0; it < 8; ++it) {
        int nx = it + 1, nb = nx & 1, cb = it & 1;
        if (it < 7) {
            int k0n = nx * 64;
#pragma unroll
            for (int p = 0; p < 4; ++p)
                av[p] = *(const float4*)(xg + (size_t)arow[p] * HH + k0n + af4[p] * 4);
#pragma unroll
            for (int s = 0; s < 6; ++s) {
                int ci = t + s * 256;
                int grow = ci >> 3, gcol = ((ci & 7) ^ (grow & 7)) << 3;
                async_cp16(kqvwT + (size_t)grow * 512 + k0n + gcol, &Bs_[nb][ci * 8]);
            }
        }
        // MFMA on current buffers (hides the A-load latency above)
        const u16* Ap = &As_[cb][0];
        const u16* Bp = &Bs_[cb][0];
#pragma unroll
        for (int kk = 0; kk < 2; ++kk) {
            int j0 = kk * 4 + q16;
            bf16x8 a[2];
#pragma unroll
            for (int i = 0; i < 2; ++i)
                a[i] = *(const bf16x8*)(Ap + (wm + i * 16 + l15) * 72 + kk * 32 + q8);
#pragma unroll
            for (int j = 0; j < 6; ++j) {
                int n = wn + j * 16 + l15;
                bf16x8 bb = *(const bf16x8*)(Bp + (n * 8 + (j0 ^ (n & 7))) * 8);
#pragma unroll
                for (int i = 0; i < 2; ++i)
                    acc[i][j] = __builtin_amdgcn_mfma_f32_16x16x32_bf16(a[i], bb, acc[i][j], 0, 0, 0);
            }
        }
        if (it < 7) {
#pragma unroll
            for (int p = 0; p < 4; ++p) {
                ushort4 pk;
                pk.x = f2bu(av[p].x); pk.y = f2bu(av[p].y);
                pk.z = f2bu(av[p].z); pk.w = f2bu(av[p].w);
                *(ushort4*)(&As_[nb][arow[p] * 72 + af4[p] * 4]) = pk;
            }
        }
        __syncthreads();
    }

    // ---- epilogue: +bias; stage k/q/vT via LDS; coalesced dumps ----
    u16* Ks = &As_[0][0];                       // 64x64 = 4096 u16
    u16* Qs = &As_[1][0];                       // 64x64 = 4096 u16
    u16* Vs = &Bs_[0][0];                       // 64x72 = 4608 u16 (pad 72)
    int rq = q16 * 4;
#pragma unroll
    for (int i = 0; i < 2; ++i) {
#pragma unroll
        for (int j = 0; j < 6; ++j) {
            int n = wn + j * 16 + l15;
            float bias = kqvb[n];
#pragma unroll
            for (int rr = 0; rr < 4; ++rr) {
                int m = wm + i * 16 + rq + rr;
                u16 hv = f2bu(acc[i][j][rr] + bias);
                if (n < 64)       Ks[m * 64 + n] = hv;
                else if (n < 128) Qs[m * 64 + (n - 64)] = hv;
                else              Vs[(n - 128) * 72 + m] = hv;
            }
        }
    }
    __syncthreads();
    {
        size_t base = (size_t)R0 * 64 + t * 16;
        *(uint4*)(kb + base)     = *(const uint4*)(Ks + t * 16);
        *(uint4*)(kb + base + 8) = *(const uint4*)(Ks + t * 16 + 8);
        *(uint4*)(qb + base)     = *(const uint4*)(Qs + t * 16);
        *(uint4*)(qb + base + 8) = *(const uint4*)(Qs + t * 16 + 8);
        int d = t >> 2, ls = (t & 3) * 16;
        u16* vd = vT + ((size_t)(b * 64 + d)) * 512 + l0 + ls;
        *(uint4*)(vd)     = *(const uint4*)(Vs + d * 72 + ls);
        *(uint4*)(vd + 8) = *(const uint4*)(Vs + d * 72 + ls + 8);
    }
}

// ========== MFMA flash attention, split-K across 4 waves (unchanged) ==========
#define VLD 136
__global__ __launch_bounds__(256, 4)
void attn_kernel(const u16* __restrict__ qb, const u16* __restrict__ kb,
                 const u16* __restrict__ vT, u16* __restrict__ head) {
    __shared__ u16 Ps[4 * 16 * VLD];
    __shared__ float Osh[4][16 * 65];
    __shared__ float Msh[4][16], Lsh[4][16];
    int b = blockIdx.y, q0 = blockIdx.x * 16;
    int t = threadIdx.x, lane = t & 63, w = t >> 6;
    int l15 = lane & 15, q16 = lane >> 4, q8 = q16 * 8;
    int kc = w * 128;
    const u16* qg = qb + (size_t)b * LL * DA;
    const u16* kg = kb + (size_t)b * LL * DA;
    const u16* vg = vT + (size_t)b * DA * LL;

    bf16x8 aq[2];
#pragma unroll
    for (int s = 0; s < 2; ++s)
        aq[s] = *(const bf16x8*)(qg + (size_t)(q0 + l15) * DA + s * 32 + q8);

    f32x4 sc[8] = {};
#pragma unroll
    for (int j = 0; j < 8; ++j) {
#pragma unroll
        for (int s = 0; s < 2; ++s) {
            bf16x8 bk = *(const bf16x8*)(kg + (size_t)(kc + j * 16 + l15) * DA + s * 32 + q8);
            sc[j] = __builtin_amdgcn_mfma_f32_16x16x32_bf16(aq[s], bk, sc[j], 0, 0, 0);
        }
    }
    float mx[4], sm[4];
#pragma unroll
    for (int j = 0; j < 8; ++j)
#pragma unroll
        for (int rr = 0; rr < 4; ++rr) sc[j][rr] *= 0.125f;
#pragma unroll
    for (int rr = 0; rr < 4; ++rr) {
        float m0 = sc[0][rr];
#pragma unroll
        for (int j = 1; j < 8; ++j) m0 = fmaxf(m0, sc[j][rr]);
        m0 = fmaxf(m0, __shfl_xor(m0, 1));
        m0 = fmaxf(m0, __shfl_xor(m0, 2));
        m0 = fmaxf(m0, __shfl_xor(m0, 4));
        m0 = fmaxf(m0, __shfl_xor(m0, 8));
        mx[rr] = m0;
    }
#pragma unroll
    for (int j = 0; j < 8; ++j)
#pragma unroll
        for (int rr = 0; rr < 4; ++rr) sc[j][rr] = __expf(sc[j][rr] - mx[rr]);
#pragma unroll
    for (int rr = 0; rr < 4; ++rr) {
        float s0 = sc[0][rr];
#pragma unroll
        for (int j = 1; j < 8; ++j) s0 += sc[j][rr];
        s0 += __shfl_xor(s0, 1);
        s0 += __shfl_xor(s0, 2);
        s0 += __shfl_xor(s0, 4);
        s0 += __shfl_xor(s0, 8);
        sm[rr] = s0;
    }
    u16* Pw = Ps + w * 16 * VLD;
#pragma unroll
    for (int j = 0; j < 8; ++j)
#pragma unroll
        for (int rr = 0; rr < 4; ++rr)
            Pw[(q16 * 4 + rr) * VLD + j * 16 + l15] = f2bu(sc[j][rr]);
    f32x4 o[4] = {};
#pragma unroll
    for (int kt = 0; kt < 4; ++kt) {
        bf16x8 ap = *(const bf16x8*)(Pw + l15 * VLD + kt * 32 + q8);
#pragma unroll
        for (int j = 0; j < 4; ++j) {
            bf16x8 bv = *(const bf16x8*)(vg + (size_t)(j * 16 + l15) * LL + kc + kt * 32 + q8);
            o[j] = __builtin_amdgcn_mfma_f32_16x16x32_bf16(ap, bv, o[j], 0, 0, 0);
        }
    }
#pragma unroll
    for (int j = 0; j < 4; ++j)
#pragma unroll
        for (int rr = 0; rr < 4; ++rr)
            Osh[w][(q16 * 4 + rr) * 65 + j * 16 + l15] = o[j][rr];
    if (l15 == 0) {
#pragma unroll
        for (int rr = 0; rr < 4; ++rr) {
            Msh[w][q16 * 4 + rr] = mx[rr];
            Lsh[w][q16 * 4 + rr] = sm[rr];
        }
    }
    __syncthreads();
    int qq = t >> 4, dg = (t & 15) * 4;
    float m0 = Msh[0][qq], m1 = Msh[1][qq], m2 = Msh[2][qq], m3 = Msh[3][qq];
    float ms = fmaxf(fmaxf(m0, m1), fmaxf(m2, m3));
    float f0 = __expf(m0 - ms), f1 = __expf(m1 - ms), f2 = __expf(m2 - ms), f3 = __expf(m3 - ms);
    float lst = Lsh[0][qq] * f0 + Lsh[1][qq] * f1 + Lsh[2][qq] * f2 + Lsh[3][qq] * f3;
    float inv = 1.0f / lst;
    ushort4 res;
    u16* rp = (u16*)&res;
#pragma unroll
    for (int i = 0; i < 4; ++i) {
        int idx = qq * 65 + dg + i;
        float a = Osh[0][idx] * f0 + Osh[1][idx] * f1 + Osh[2][idx] * f2 + Osh[3][idx] * f3;
        rp[i] = f2bu(a * inv);
    }
    *(ushort4*)(head + (size_t)(b * LL + q0 + qq) * DA + dg) = res;
}

// ========== fused Toeplitz GEMM + proj + bias + gate (unchanged) ==========
__device__ __forceinline__ void mfma_tile64(const u16* As, const u16* Bs,
                                            f32x4 acc[4][4], int wm, int wn,
                                            int l15, int q16) {
    int s7 = l15 & 7;
#pragma unroll
    for (int kk = 0; kk < 2; ++kk) {
        int j0 = kk * 4 + q16;
        bf16x8 a[4], bv[4];
#pragma unroll
        for (int i = 0; i < 4; ++i) {
            int row = wm + i * 16 + l15;
            a[i] = *(const bf16x8*)(As + (row * 8 + (j0 ^ s7)) * 8);
        }
#pragma unroll
        for (int j = 0; j < 4; ++j) {
            int row = wn + j * 16 + l15;
            bv[j] = *(const bf16x8*)(Bs + (row * 8 + (j0 ^ s7)) * 8);
        }
#pragma unroll
        for (int i = 0; i < 4; ++i)
#pragma unroll
            for (int j = 0; j < 4; ++j)
                acc[i][j] = __builtin_amdgcn_mfma_f32_16x16x32_bf16(a[i], bv[j], acc[i][j], 0, 0, 0);
    }
}

__device__ __forceinline__ void stage_pair(const u16* A, const u16* B, int ldk,
                                           int koff, u16* Ad, u16* Bd, int t) {
#pragma unroll
    for (int s = 0; s < 4; ++s) {
        int ci = t + s * 256;
        int grow = ci >> 3, gcol = ((ci & 7) ^ (grow & 7)) << 3;
        async_cp16(A + (size_t)grow * ldk + koff + gcol, Ad + ci * 8);
        async_cp16(B + (size_t)grow * ldk + koff + gcol, Bd + ci * 8);
    }
}

__global__ __launch_bounds__(256, 2)
void mix_kernel(const u16* __restrict__ wt,      // [512 m][512 l]
                const u16* __restrict__ vnT,     // [B][512 c][512 l]
                const u16* __restrict__ headb,   // [B][512 m][64 d]
                const u16* __restrict__ projwT,  // [512 c][64 d]
                const float* __restrict__ x,
                const float* __restrict__ tbias,
                const float* __restrict__ projb,
                float* __restrict__ out) {
    __shared__ u16 As[2][128 * 64];              // 2 x 16 KiB
    __shared__ u16 Bs[2][128 * 64];              // 2 x 16 KiB  (total 64 KiB, 2 blk/CU)
    int lid = blockIdx.x;
    int p8 = lid & 7, rest = lid >> 3;
    int mi = rest & 3, pair = (rest >> 2) * 8 + p8;   // pair in [0,128)
    int b = pair >> 2, m0 = mi * 128, c0 = (pair & 3) * 128;
    int t = threadIdx.x, lane = t & 63, wid = t >> 6;
    int wm = (wid >> 1) * 64, wn = (wid & 1) * 64;
    int l15 = lane & 15, q16 = lane >> 4;
    f32x4 acc[4][4] = {};
    const u16* Ag = wt + (size_t)m0 * 512;
    const u16* Bg = vnT + ((size_t)b * H2 + c0) * 512;
    const u16* Hg = headb + ((size_t)b * LL + m0) * DA;
    const u16* Pg = projwT + (size_t)c0 * DA;

    // prologue: stage tile 0 (Toeplitz k0=0) into buf 0
    stage_pair(Ag, Bg, 512, 0, As[0], Bs[0], t);
    __syncthreads();                             // drains DMA

    // 9-tile pipeline: 8 Toeplitz K-slabs + proj as tile 8; stage-next ∥ MFMA-current
    for (int it = 0; it < 9; ++it) {
        int nx = it + 1;
        if (nx < 8)
            stage_pair(Ag, Bg, 512, nx * 64, As[nx & 1], Bs[nx & 1], t);
        else if (nx == 8)
            stage_pair(Hg, Pg, 64, 0, As[0], Bs[0], t);
        mfma_tile64(As[it & 1], Bs[it & 1], acc, wm, wn, l15, q16);
        __syncthreads();                         // next-buf ready; cur buf released
    }

    int rq = q16 * 4;
#pragma unroll
    for (int i = 0; i < 4; ++i) {
#pragma unroll
        for (int rr = 0; rr < 4; ++rr) {
            int m = m0 + wm + i * 16 + rq + rr;
            float tb = tbias[m];
            const float* xrow = x + ((size_t)b * LL + m) * HH;
            float* orow = out + ((size_t)b * LL + m) * H2;
#pragma unroll
            for (int j = 0; j < 4; ++j) {
                int c = c0 + wn + j * 16 + l15;
                float val = acc[i][j][rr] + tb + projb[c];
                orow[c] = xrow[c] * val;
            }
        }
    }
}

extern "C" void kernel_launch(void* const* d_in, const int* in_sizes, int n_in,
                              void* d_out, int out_size, void* d_ws, size_t ws_size,
                              hipStream_t stream) {
    (void)in_sizes; (void)n_in; (void)out_size; (void)ws_size;
    const float* x     = (const float*)d_in[0];
    const float* gamma = (const float*)d_in[1];
    const float* beta  = (const float*)d_in[2];
    const float* wv    = (const float*)d_in[3];
    const float* tb    = (const float*)d_in[4];
    const float* kqvw  = (const float*)d_in[5];
    const float* kqvb  = (const float*)d_in[6];
    const float* projw = (const float*)d_in[7];
    const float* projb = (const float*)d_in[8];
    float* out = (float*)d_out;

    u16* vnT_bf  = (u16*)d_ws;                          // 16 MB
    u16* qb      = vnT_bf + (size_t)NB * LL * H2;       // 2 MB
    u16* kb      = qb + (size_t)NB * LL * DA;           // 2 MB
    u16* vTb     = kb + (size_t)NB * LL * DA;           // 2 MB
    u16* head_bf = vTb + (size_t)NB * LL * DA;          // 2 MB
    u16* wt_bf   = head_bf + (size_t)NB * LL * DA;      // 512 KB
    u16* kqvwT   = wt_bf + 512 * 512;                   // 192 KB
    u16* projwT  = kqvwT + 192 * 512;                   // 64 KB

    prep_kernel <<<1536, 256, 0, stream>>>(wv, kqvw, projw, wt_bf, kqvwT, projwT);
    front_kernel<<<512, 512, 0, stream>>>(x, gamma, beta, vnT_bf);
    kqv_kernel  <<<256, 256, 0, stream>>>(x, kqvwT, kqvb, qb, kb, vTb);
    attn_kernel <<<dim3(32, NB), 256, 0, stream>>>(qb, kb, vTb, head_bf);
    mix_kernel  <<<512, 256, 0, stream>>>(wt_bf, vnT_bf, head_bf, projwT,
                                          x, tb, projb, out);
}

// Round 5
// 173.570 us; speedup vs baseline: 1.1623x; 1.0451x over previous
//
#include <hip/hip_runtime.h>
#include <math.h>

#define NB 32
#define LL 512
#define HH 1024
#define H2 512
#define DA 64

typedef unsigned int u32;
typedef unsigned short u16;
typedef __bf16 bf16x8 __attribute__((ext_vector_type(8)));
typedef float f32x4 __attribute__((ext_vector_type(4)));
typedef u16 u16x8 __attribute__((ext_vector_type(8)));

__device__ __forceinline__ u16 f2bu(float f) {          // fp32 -> bf16 bits, RNE
    u32 u = __builtin_bit_cast(u32, f);
    u = (u + 0x7fff + ((u >> 16) & 1)) >> 16;
    return (u16)u;
}

__device__ __forceinline__ float b2f(u16 u) {           // bf16 bits -> fp32
    u32 v = (u32)u << 16;
    return __builtin_bit_cast(float, v);
}

__device__ __forceinline__ void async_cp16(const void* g, void* l) {
    __builtin_amdgcn_global_load_lds(
        (const __attribute__((address_space(1))) u32*)g,
        (__attribute__((address_space(3))) u32*)l, 16, 0, 0);
}

// ========== prep: bf16 weight materialization (unchanged) ==========
__global__ void prep_kernel(const float* __restrict__ wv,
                            const float* __restrict__ kqvw,
                            const float* __restrict__ projw,
                            u16* __restrict__ wt, u16* __restrict__ kqvwT,
                            u16* __restrict__ projwT) {
    int e = blockIdx.x * 256 + threadIdx.x;
    if (e < 262144) {
        int m = e >> 9, l = e & 511;
        wt[e] = f2bu(wv[511 + m - l]);
    } else if (e < 262144 + 98304) {
        int i = e - 262144;
        int n = i >> 9, k = i & 511;
        kqvwT[i] = f2bu(kqvw[(size_t)k * 192 + n]);
    } else {
        int i = e - 360448;
        int c = i >> 6, d = i & 63;
        projwT[i] = f2bu(projw[(size_t)d * 512 + c]);
    }
}

// ========== v_kernel: fused LN-stats + affine-transpose + kqv GEMM ==========
// 256 blocks (1/CU) x 256 threads, 64 rows each. One x read total:
//  - A-tile = raw bf16(v), FULL 64x512 retained in LDS (XOR-granule swizzle,
//    conflict-free MFMA reads), staged once per K-step with LN sums
//    accumulated in-register during the loads (tiny-attn uses RAW v).
//  - B (kqvwT, L2-resident) double-buffered via swizzled global_load_lds.
//  - epilogue A: +bias, k/q/val outputs via LDS for coalesced dumps.
//  - epilogue B: LN affine from retained A-tile -> vnT (replaces front_kernel).
__global__ __launch_bounds__(256, 1)
void v_kernel(const float* __restrict__ x,
              const u16* __restrict__ kqvwT, const float* __restrict__ kqvb,
              const float* __restrict__ gamma, const float* __restrict__ beta,
              u16* __restrict__ vnT,
              u16* __restrict__ qb, u16* __restrict__ kb, u16* __restrict__ vT) {
    __shared__ u16 Af[64 * 64 * 8];             // 64 KiB: row r, granule g at slot g^(r&7)
    __shared__ u16 Bs_[2][192 * 64];            // 2 x 24 KiB
    __shared__ float MU[64], RS[64];
    int blk = blockIdx.x, t = threadIdx.x;
    int R0 = blk * 64, b = R0 >> 9, l0 = R0 & 511;
    int lane = t & 63, wid = t >> 6;
    int l15 = lane & 15, q16 = lane >> 4, q8 = q16 * 8;
    int wm = (wid & 1) * 32, wn = (wid >> 1) * 96;
    const float* xg = x + (size_t)R0 * HH + H2;

    // A-stage mapping: chunk p, flat = t + p*256; row = flat>>4, f4 = flat&15
    int arow[4], af4[4], sgg[4], shalf[4];
#pragma unroll
    for (int p = 0; p < 4; ++p) {
        int flat = t + p * 256;
        arow[p] = flat >> 4; af4[p] = flat & 15;
        sgg[p] = (af4[p] >> 1) ^ (arow[p] & 7);   // swizzled granule within slab
        shalf[p] = (af4[p] & 1) * 4;
    }

    float s1[4] = {0.f, 0.f, 0.f, 0.f}, s2[4] = {0.f, 0.f, 0.f, 0.f};
    float4 av[4];
    f32x4 acc[2][6] = {};

    // ---- prologue: issue Bs[0]; load+accumulate+write A slab 0 ----
#pragma unroll
    for (int s = 0; s < 6; ++s) {
        int ci = t + s * 256;
        int grow = ci >> 3, gcol = ((ci & 7) ^ (grow & 7)) << 3;
        async_cp16(kqvwT + (size_t)grow * 512 + gcol, &Bs_[0][ci * 8]);
    }
#pragma unroll
    for (int p = 0; p < 4; ++p)
        av[p] = *(const float4*)(xg + (size_t)arow[p] * HH + af4[p] * 4);
#pragma unroll
    for (int p = 0; p < 4; ++p) {
        s1[p] += av[p].x + av[p].y + av[p].z + av[p].w;
        s2[p] += av[p].x * av[p].x + av[p].y * av[p].y
               + av[p].z * av[p].z + av[p].w * av[p].w;
        ushort4 pk;
        pk.x = f2bu(av[p].x); pk.y = f2bu(av[p].y);
        pk.z = f2bu(av[p].z); pk.w = f2bu(av[p].w);
        *(ushort4*)(&Af[(arow[p] * 64 + sgg[p]) * 8 + shalf[p]]) = pk;
    }
    __syncthreads();

    // ---- 8-step pipeline: issue next loads -> MFMA current -> write next A ----
    for (int it = 0; it < 8; ++it) {
        int nx = it + 1, nb = nx & 1, cb = it & 1;
        if (it < 7) {
            int k0n = nx * 64;
#pragma unroll
            for (int p = 0; p < 4; ++p)
                av[p] = *(const float4*)(xg + (size_t)arow[p] * HH + k0n + af4[p] * 4);
#pragma unroll
            for (int s = 0; s < 6; ++s) {
                int ci = t + s * 256;
                int grow = ci >> 3, gcol = ((ci & 7) ^ (grow & 7)) << 3;
                async_cp16(kqvwT + (size_t)grow * 512 + k0n + gcol, &Bs_[nb][ci * 8]);
            }
        }
        // MFMA on current A slab + B buffer
        const u16* Bp = &Bs_[cb][0];
#pragma unroll
        for (int kk = 0; kk < 2; ++kk) {
            int j0 = kk * 4 + q16;
            int g = it * 8 + kk * 4 + q16;
            bf16x8 a[2];
#pragma unroll
            for (int i = 0; i < 2; ++i) {
                int row = wm + i * 16 + l15;
                a[i] = *(const bf16x8*)(&Af[(row * 64 + (g ^ (row & 7))) * 8]);
            }
#pragma unroll
            for (int j = 0; j < 6; ++j) {
                int n = wn + j * 16 + l15;
                bf16x8 bb = *(const bf16x8*)(Bp + (n * 8 + (j0 ^ (n & 7))) * 8);
#pragma unroll
                for (int i = 0; i < 2; ++i)
                    acc[i][j] = __builtin_amdgcn_mfma_f32_16x16x32_bf16(a[i], bb, acc[i][j], 0, 0, 0);
            }
        }
        if (it < 7) {
            int k0n = nx * 64;
#pragma unroll
            for (int p = 0; p < 4; ++p) {
                s1[p] += av[p].x + av[p].y + av[p].z + av[p].w;
                s2[p] += av[p].x * av[p].x + av[p].y * av[p].y
                       + av[p].z * av[p].z + av[p].w * av[p].w;
                ushort4 pk;
                pk.x = f2bu(av[p].x); pk.y = f2bu(av[p].y);
                pk.z = f2bu(av[p].z); pk.w = f2bu(av[p].w);
                *(ushort4*)(&Af[(arow[p] * 64 + nx * 8 + sgg[p]) * 8 + shalf[p]]) = pk;
            }
        }
        __syncthreads();
    }

    // ---- LN stats: 16-lane group reduce (threads g*16+m share rows p*16+g) ----
#pragma unroll
    for (int p = 0; p < 4; ++p) {
        s1[p] += __shfl_xor(s1[p], 1); s2[p] += __shfl_xor(s2[p], 1);
        s1[p] += __shfl_xor(s1[p], 2); s2[p] += __shfl_xor(s2[p], 2);
        s1[p] += __shfl_xor(s1[p], 4); s2[p] += __shfl_xor(s2[p], 4);
        s1[p] += __shfl_xor(s1[p], 8); s2[p] += __shfl_xor(s2[p], 8);
    }
    if ((t & 15) == 0) {
        int g = t >> 4;
#pragma unroll
        for (int p = 0; p < 4; ++p) {
            float mu = s1[p] * (1.0f / H2);
            float rstd = rsqrtf(s2[p] * (1.0f / H2) - mu * mu + 1e-5f);
            MU[p * 16 + g] = mu; RS[p * 16 + g] = rstd;
        }
    }

    // ---- epilogue A: +bias; k/q/val via LDS (alias Bs); coalesced dumps ----
    u16* Ks = &Bs_[0][0];                       // 64x64 = 4096 u16
    u16* Qs = &Bs_[0][4096];                    // 64x64 = 4096 u16
    u16* Vs = &Bs_[1][0];                       // 64x72 = 4608 u16 (pad 72)
    int rq = q16 * 4;
#pragma unroll
    for (int i = 0; i < 2; ++i) {
#pragma unroll
        for (int j = 0; j < 6; ++j) {
            int n = wn + j * 16 + l15;
            float bias = kqvb[n];
#pragma unroll
            for (int rr = 0; rr < 4; ++rr) {
                int m = wm + i * 16 + rq + rr;
                u16 hv = f2bu(acc[i][j][rr] + bias);
                if (n < 64)       Ks[m * 64 + n] = hv;
                else if (n < 128) Qs[m * 64 + (n - 64)] = hv;
                else              Vs[(n - 128) * 72 + m] = hv;
            }
        }
    }
    __syncthreads();                            // also publishes MU/RS
    {
        size_t base = (size_t)R0 * 64 + t * 16;
        *(uint4*)(kb + base)     = *(const uint4*)(Ks + t * 16);
        *(uint4*)(kb + base + 8) = *(const uint4*)(Ks + t * 16 + 8);
        *(uint4*)(qb + base)     = *(const uint4*)(Qs + t * 16);
        *(uint4*)(qb + base + 8) = *(const uint4*)(Qs + t * 16 + 8);
        int d = t >> 2, ls = (t & 3) * 16;
        u16* vd = vT + ((size_t)(b * 64 + d)) * 512 + l0 + ls;
        *(uint4*)(vd)     = *(const uint4*)(Vs + d * 72 + ls);
        *(uint4*)(vd + 8) = *(const uint4*)(Vs + d * 72 + ls + 8);
    }

    // ---- epilogue B: LN affine from Af -> vnT (replaces front_kernel) ----
    {
        int c0 = 2 * t;                         // two adjacent columns per thread
        float ga0 = gamma[c0], ga1 = gamma[c0 + 1];
        float be0 = beta[c0],  be1 = beta[c0 + 1];
        u16* d0 = vnT + ((size_t)(b * H2 + c0)) * LL + l0;
        u16* d1 = d0 + LL;
        int gbase = t >> 2;                     // absolute granule of c0 (c0>>3)
        int coff = c0 & 7;
#pragma unroll
        for (int lc = 0; lc < 8; ++lc) {
            u16x8 o0, o1;
#pragma unroll
            for (int li = 0; li < 8; ++li) {
                int l = lc * 8 + li;
                u32 w = *(const u32*)(&Af[(l * 64 + (gbase ^ (l & 7))) * 8 + coff]);
                float mu = MU[l], rs = RS[l];
                o0[li] = f2bu((b2f((u16)w)         - mu) * rs * ga0 + be0);
                o1[li] = f2bu((b2f((u16)(w >> 16)) - mu) * rs * ga1 + be1);
            }
            *(u16x8*)(d0 + lc * 8) = o0;
            *(u16x8*)(d1 + lc * 8) = o1;
        }
    }
}

// ========== MFMA flash attention, split-K across 4 waves (unchanged) ==========
#define VLD 136
__global__ __launch_bounds__(256, 4)
void attn_kernel(const u16* __restrict__ qb, const u16* __restrict__ kb,
                 const u16* __restrict__ vT, u16* __restrict__ head) {
    __shared__ u16 Ps[4 * 16 * VLD];
    __shared__ float Osh[4][16 * 65];
    __shared__ float Msh[4][16], Lsh[4][16];
    int b = blockIdx.y, q0 = blockIdx.x * 16;
    int t = threadIdx.x, lane = t & 63, w = t >> 6;
    int l15 = lane & 15, q16 = lane >> 4, q8 = q16 * 8;
    int kc = w * 128;
    const u16* qg = qb + (size_t)b * LL * DA;
    const u16* kg = kb + (size_t)b * LL * DA;
    const u16* vg = vT + (size_t)b * DA * LL;

    bf16x8 aq[2];
#pragma unroll
    for (int s = 0; s < 2; ++s)
        aq[s] = *(const bf16x8*)(qg + (size_t)(q0 + l15) * DA + s * 32 + q8);

    f32x4 sc[8] = {};
#pragma unroll
    for (int j = 0; j < 8; ++j) {
#pragma unroll
        for (int s = 0; s < 2; ++s) {
            bf16x8 bk = *(const bf16x8*)(kg + (size_t)(kc + j * 16 + l15) * DA + s * 32 + q8);
            sc[j] = __builtin_amdgcn_mfma_f32_16x16x32_bf16(aq[s], bk, sc[j], 0, 0, 0);
        }
    }
    float mx[4], sm[4];
#pragma unroll
    for (int j = 0; j < 8; ++j)
#pragma unroll
        for (int rr = 0; rr < 4; ++rr) sc[j][rr] *= 0.125f;
#pragma unroll
    for (int rr = 0; rr < 4; ++rr) {
        float m0 = sc[0][rr];
#pragma unroll
        for (int j = 1; j < 8; ++j) m0 = fmaxf(m0, sc[j][rr]);
        m0 = fmaxf(m0, __shfl_xor(m0, 1));
        m0 = fmaxf(m0, __shfl_xor(m0, 2));
        m0 = fmaxf(m0, __shfl_xor(m0, 4));
        m0 = fmaxf(m0, __shfl_xor(m0, 8));
        mx[rr] = m0;
    }
#pragma unroll
    for (int j = 0; j < 8; ++j)
#pragma unroll
        for (int rr = 0; rr < 4; ++rr) sc[j][rr] = __expf(sc[j][rr] - mx[rr]);
#pragma unroll
    for (int rr = 0; rr < 4; ++rr) {
        float s0 = sc[0][rr];
#pragma unroll
        for (int j = 1; j < 8; ++j) s0 += sc[j][rr];
        s0 += __shfl_xor(s0, 1);
        s0 += __shfl_xor(s0, 2);
        s0 += __shfl_xor(s0, 4);
        s0 += __shfl_xor(s0, 8);
        sm[rr] = s0;
    }
    u16* Pw = Ps + w * 16 * VLD;
#pragma unroll
    for (int j = 0; j < 8; ++j)
#pragma unroll
        for (int rr = 0; rr < 4; ++rr)
            Pw[(q16 * 4 + rr) * VLD + j * 16 + l15] = f2bu(sc[j][rr]);
    f32x4 o[4] = {};
#pragma unroll
    for (int kt = 0; kt < 4; ++kt) {
        bf16x8 ap = *(const bf16x8*)(Pw + l15 * VLD + kt * 32 + q8);
#pragma unroll
        for (int j = 0; j < 4; ++j) {
            bf16x8 bv = *(const bf16x8*)(vg + (size_t)(j * 16 + l15) * LL + kc + kt * 32 + q8);
            o[j] = __builtin_amdgcn_mfma_f32_16x16x32_bf16(ap, bv, o[j], 0, 0, 0);
        }
    }
#pragma unroll
    for (int j = 0; j < 4; ++j)
#pragma unroll
        for (int rr = 0; rr < 4; ++rr)
            Osh[w][(q16 * 4 + rr) * 65 + j * 16 + l15] = o[j][rr];
    if (l15 == 0) {
#pragma unroll
        for (int rr = 0; rr < 4; ++rr) {
            Msh[w][q16 * 4 + rr] = mx[rr];
            Lsh[w][q16 * 4 + rr] = sm[rr];
        }
    }
    __syncthreads();
    int qq = t >> 4, dg = (t & 15) * 4;
    float m0 = Msh[0][qq], m1 = Msh[1][qq], m2 = Msh[2][qq], m3 = Msh[3][qq];
    float ms = fmaxf(fmaxf(m0, m1), fmaxf(m2, m3));
    float f0 = __expf(m0 - ms), f1 = __expf(m1 - ms), f2 = __expf(m2 - ms), f3 = __expf(m3 - ms);
    float lst = Lsh[0][qq] * f0 + Lsh[1][qq] * f1 + Lsh[2][qq] * f2 + Lsh[3][qq] * f3;
    float inv = 1.0f / lst;
    ushort4 res;
    u16* rp = (u16*)&res;
#pragma unroll
    for (int i = 0; i < 4; ++i) {
        int idx = qq * 65 + dg + i;
        float a = Osh[0][idx] * f0 + Osh[1][idx] * f1 + Osh[2][idx] * f2 + Osh[3][idx] * f3;
        rp[i] = f2bu(a * inv);
    }
    *(ushort4*)(head + (size_t)(b * LL + q0 + qq) * DA + dg) = res;
}

// ========== fused Toeplitz GEMM + proj + bias + gate (unchanged) ==========
__device__ __forceinline__ void mfma_tile64(const u16* As, const u16* Bs,
                                            f32x4 acc[4][4], int wm, int wn,
                                            int l15, int q16) {
    int s7 = l15 & 7;
#pragma unroll
    for (int kk = 0; kk < 2; ++kk) {
        int j0 = kk * 4 + q16;
        bf16x8 a[4], bv[4];
#pragma unroll
        for (int i = 0; i < 4; ++i) {
            int row = wm + i * 16 + l15;
            a[i] = *(const bf16x8*)(As + (row * 8 + (j0 ^ s7)) * 8);
        }
#pragma unroll
        for (int j = 0; j < 4; ++j) {
            int row = wn + j * 16 + l15;
            bv[j] = *(const bf16x8*)(Bs + (row * 8 + (j0 ^ s7)) * 8);
        }
#pragma unroll
        for (int i = 0; i < 4; ++i)
#pragma unroll
            for (int j = 0; j < 4; ++j)
                acc[i][j] = __builtin_amdgcn_mfma_f32_16x16x32_bf16(a[i], bv[j], acc[i][j], 0, 0, 0);
    }
}

__device__ __forceinline__ void stage_pair(const u16* A, const u16* B, int ldk,
                                           int koff, u16* Ad, u16* Bd, int t) {
#pragma unroll
    for (int s = 0; s < 4; ++s) {
        int ci = t + s * 256;
        int grow = ci >> 3, gcol = ((ci & 7) ^ (grow & 7)) << 3;
        async_cp16(A + (size_t)grow * ldk + koff + gcol, Ad + ci * 8);
        async_cp16(B + (size_t)grow * ldk + koff + gcol, Bd + ci * 8);
    }
}

__global__ __launch_bounds__(256, 2)
void mix_kernel(const u16* __restrict__ wt,      // [512 m][512 l]
                const u16* __restrict__ vnT,     // [B][512 c][512 l]
                const u16* __restrict__ headb,   // [B][512 m][64 d]
                const u16* __restrict__ projwT,  // [512 c][64 d]
                const float* __restrict__ x,
                const float* __restrict__ tbias,
                const float* __restrict__ projb,
                float* __restrict__ out) {
    __shared__ u16 As[2][128 * 64];              // 2 x 16 KiB
    __shared__ u16 Bs[2][128 * 64];              // 2 x 16 KiB  (total 64 KiB, 2 blk/CU)
    int lid = blockIdx.x;
    int p8 = lid & 7, rest = lid >> 3;
    int mi = rest & 3, pair = (rest >> 2) * 8 + p8;   // pair in [0,128)
    int b = pair >> 2, m0 = mi * 128, c0 = (pair & 3) * 128;
    int t = threadIdx.x, lane = t & 63, wid = t >> 6;
    int wm = (wid >> 1) * 64, wn = (wid & 1) * 64;
    int l15 = lane & 15, q16 = lane >> 4;
    f32x4 acc[4][4] = {};
    const u16* Ag = wt + (size_t)m0 * 512;
    const u16* Bg = vnT + ((size_t)b * H2 + c0) * 512;
    const u16* Hg = headb + ((size_t)b * LL + m0) * DA;
    const u16* Pg = projwT + (size_t)c0 * DA;

    // prologue: stage tile 0 (Toeplitz k0=0) into buf 0
    stage_pair(Ag, Bg, 512, 0, As[0], Bs[0], t);
    __syncthreads();                             // drains DMA

    // 9-tile pipeline: 8 Toeplitz K-slabs + proj as tile 8; stage-next ∥ MFMA-current
    for (int it = 0; it < 9; ++it) {
        int nx = it + 1;
        if (nx < 8)
            stage_pair(Ag, Bg, 512, nx * 64, As[nx & 1], Bs[nx & 1], t);
        else if (nx == 8)
            stage_pair(Hg, Pg, 64, 0, As[0], Bs[0], t);
        mfma_tile64(As[it & 1], Bs[it & 1], acc, wm, wn, l15, q16);
        __syncthreads();                         // next-buf ready; cur buf released
    }

    int rq = q16 * 4;
#pragma unroll
    for (int i = 0; i < 4; ++i) {
#pragma unroll
        for (int rr = 0; rr < 4; ++rr) {
            int m = m0 + wm + i * 16 + rq + rr;
            float tb = tbias[m];
            const float* xrow = x + ((size_t)b * LL + m) * HH;
            float* orow = out + ((size_t)b * LL + m) * H2;
#pragma unroll
            for (int j = 0; j < 4; ++j) {
                int c = c0 + wn + j * 16 + l15;
                float val = acc[i][j][rr] + tb + projb[c];
                orow[c] = xrow[c] * val;
            }
        }
    }
}

extern "C" void kernel_launch(void* const* d_in, const int* in_sizes, int n_in,
                              void* d_out, int out_size, void* d_ws, size_t ws_size,
                              hipStream_t stream) {
    (void)in_sizes; (void)n_in; (void)out_size; (void)ws_size;
    const float* x     = (const float*)d_in[0];
    const float* gamma = (const float*)d_in[1];
    const float* beta  = (const float*)d_in[2];
    const float* wv    = (const float*)d_in[3];
    const float* tb    = (const float*)d_in[4];
    const float* kqvw  = (const float*)d_in[5];
    const float* kqvb  = (const float*)d_in[6];
    const float* projw = (const float*)d_in[7];
    const float* projb = (const float*)d_in[8];
    float* out = (float*)d_out;

    u16* vnT_bf  = (u16*)d_ws;                          // 16 MB
    u16* qb      = vnT_bf + (size_t)NB * LL * H2;       // 2 MB
    u16* kb      = qb + (size_t)NB * LL * DA;           // 2 MB
    u16* vTb     = kb + (size_t)NB * LL * DA;           // 2 MB
    u16* head_bf = vTb + (size_t)NB * LL * DA;          // 2 MB
    u16* wt_bf   = head_bf + (size_t)NB * LL * DA;      // 512 KB
    u16* kqvwT   = wt_bf + 512 * 512;                   // 192 KB
    u16* projwT  = kqvwT + 192 * 512;                   // 64 KB

    prep_kernel <<<1536, 256, 0, stream>>>(wv, kqvw, projw, wt_bf, kqvwT, projwT);
    v_kernel    <<<256, 256, 0, stream>>>(x, kqvwT, kqvb, gamma, beta,
                                          vnT_bf, qb, kb, vTb);
    attn_kernel <<<dim3(32, NB), 256, 0, stream>>>(qb, kb, vTb, head_bf);
    mix_kernel  <<<512, 256, 0, stream>>>(wt_bf, vnT_bf, head_bf, projwT,
                                          x, tb, projb, out);
}

// Round 6
// 163.508 us; speedup vs baseline: 1.2338x; 1.0615x over previous
//
#include <hip/hip_runtime.h>
#include <math.h>

#define NB 32
#define LL 512
#define HH 1024
#define H2 512
#define DA 64

typedef unsigned int u32;
typedef unsigned short u16;
typedef __bf16 bf16x8 __attribute__((ext_vector_type(8)));
typedef float f32x4 __attribute__((ext_vector_type(4)));
typedef u16 u16x8 __attribute__((ext_vector_type(8)));

__device__ __forceinline__ u16 f2bu(float f) {          // fp32 -> bf16 bits, RNE
    u32 u = __builtin_bit_cast(u32, f);
    u = (u + 0x7fff + ((u >> 16) & 1)) >> 16;
    return (u16)u;
}

__device__ __forceinline__ float b2f(u16 u) {           // bf16 bits -> fp32
    u32 v = (u32)u << 16;
    return __builtin_bit_cast(float, v);
}

__device__ __forceinline__ void async_cp16(const void* g, void* l) {
    __builtin_amdgcn_global_load_lds(
        (const __attribute__((address_space(1))) u32*)g,
        (__attribute__((address_space(3))) u32*)l, 16, 0, 0);
}

// ========== prep: bf16 weight materialization (unchanged) ==========
__global__ void prep_kernel(const float* __restrict__ wv,
                            const float* __restrict__ kqvw,
                            const float* __restrict__ projw,
                            u16* __restrict__ wt, u16* __restrict__ kqvwT,
                            u16* __restrict__ projwT) {
    int e = blockIdx.x * 256 + threadIdx.x;
    if (e < 262144) {
        int m = e >> 9, l = e & 511;
        wt[e] = f2bu(wv[511 + m - l]);
    } else if (e < 262144 + 98304) {
        int i = e - 262144;
        int n = i >> 9, k = i & 511;
        kqvwT[i] = f2bu(kqvw[(size_t)k * 192 + n]);
    } else {
        int i = e - 360448;
        int c = i >> 6, d = i & 63;
        projwT[i] = f2bu(projw[(size_t)d * 512 + c]);
    }
}

// ========== v_kernel: fused LN-stats + affine-transpose + kqv GEMM ==========
// 256 blocks x 512 threads (8 waves/CU, was 4). 64 rows per block, one x read:
//  - A-tile = raw bf16(v), FULL 64x512 retained in LDS (XOR-granule swizzle).
//  - B (kqvwT, L2-resident) double-buffered via swizzled global_load_lds.
//  - LN sums accumulate in-register during A staging.
//  - epilogue A: +bias, k/q/val via LDS for coalesced dumps.
//  - epilogue B: LN affine from retained A-tile -> vnT.
__global__ __launch_bounds__(512, 1)
void v_kernel(const float* __restrict__ x,
              const u16* __restrict__ kqvwT, const float* __restrict__ kqvb,
              const float* __restrict__ gamma, const float* __restrict__ beta,
              u16* __restrict__ vnT,
              u16* __restrict__ qb, u16* __restrict__ kb, u16* __restrict__ vT) {
    __shared__ u16 Af[64 * 64 * 8];             // 64 KiB: row r, slab s, granule g at slot s*8+(g^(r&7))
    __shared__ u16 Bs_[2][192 * 64];            // 2 x 24 KiB
    __shared__ float MU[64], RS[64];
    int blk = blockIdx.x, t = threadIdx.x;
    int R0 = blk * 64, b = R0 >> 9, l0 = R0 & 511;
    int lane = t & 63, wid = t >> 6;            // wid 0..7
    int l15 = lane & 15, q16 = lane >> 4, q8 = q16 * 8;
    int wm = (wid & 3) * 16, wn = (wid >> 2) * 96;
    const float* xg = x + (size_t)R0 * HH + H2;

    // A-stage mapping: chunk p, flat = t + p*512; row = flat>>4, f4 = flat&15
    int arow[2], af4[2], sgg[2], shalf[2];
#pragma unroll
    for (int p = 0; p < 2; ++p) {
        int flat = t + p * 512;
        arow[p] = flat >> 4; af4[p] = flat & 15;
        sgg[p] = (af4[p] >> 1) ^ (arow[p] & 7);   // swizzled granule within slab
        shalf[p] = (af4[p] & 1) * 4;
    }

    float s1[2] = {0.f, 0.f}, s2[2] = {0.f, 0.f};
    float4 av[2];
    f32x4 acc[6] = {};

    // ---- prologue: issue Bs[0]; load+accumulate+write A slab 0 ----
#pragma unroll
    for (int s = 0; s < 3; ++s) {
        int ci = t + s * 512;
        int grow = ci >> 3, gcol = ((ci & 7) ^ (grow & 7)) << 3;
        async_cp16(kqvwT + (size_t)grow * 512 + gcol, &Bs_[0][ci * 8]);
    }
#pragma unroll
    for (int p = 0; p < 2; ++p)
        av[p] = *(const float4*)(xg + (size_t)arow[p] * HH + af4[p] * 4);
#pragma unroll
    for (int p = 0; p < 2; ++p) {
        s1[p] += av[p].x + av[p].y + av[p].z + av[p].w;
        s2[p] += av[p].x * av[p].x + av[p].y * av[p].y
               + av[p].z * av[p].z + av[p].w * av[p].w;
        ushort4 pk;
        pk.x = f2bu(av[p].x); pk.y = f2bu(av[p].y);
        pk.z = f2bu(av[p].z); pk.w = f2bu(av[p].w);
        *(ushort4*)(&Af[(arow[p] * 64 + sgg[p]) * 8 + shalf[p]]) = pk;
    }
    __syncthreads();

    // ---- 8-step pipeline: issue next loads -> MFMA current -> write next A ----
    for (int it = 0; it < 8; ++it) {
        int nx = it + 1, nb = nx & 1, cb = it & 1;
        if (it < 7) {
            int k0n = nx * 64;
#pragma unroll
            for (int p = 0; p < 2; ++p)
                av[p] = *(const float4*)(xg + (size_t)arow[p] * HH + k0n + af4[p] * 4);
#pragma unroll
            for (int s = 0; s < 3; ++s) {
                int ci = t + s * 512;
                int grow = ci >> 3, gcol = ((ci & 7) ^ (grow & 7)) << 3;
                async_cp16(kqvwT + (size_t)grow * 512 + k0n + gcol, &Bs_[nb][ci * 8]);
            }
        }
        // MFMA on current A slab + B buffer
        const u16* Bp = &Bs_[cb][0];
#pragma unroll
        for (int kk = 0; kk < 2; ++kk) {
            int j0 = kk * 4 + q16;
            int g = it * 8 + kk * 4 + q16;
            int row = wm + l15;
            bf16x8 a = *(const bf16x8*)(&Af[(row * 64 + (g ^ (row & 7))) * 8]);
#pragma unroll
            for (int j = 0; j < 6; ++j) {
                int n = wn + j * 16 + l15;
                bf16x8 bb = *(const bf16x8*)(Bp + (n * 8 + (j0 ^ (n & 7))) * 8);
                acc[j] = __builtin_amdgcn_mfma_f32_16x16x32_bf16(a, bb, acc[j], 0, 0, 0);
            }
        }
        if (it < 7) {
#pragma unroll
            for (int p = 0; p < 2; ++p) {
                s1[p] += av[p].x + av[p].y + av[p].z + av[p].w;
                s2[p] += av[p].x * av[p].x + av[p].y * av[p].y
                       + av[p].z * av[p].z + av[p].w * av[p].w;
                ushort4 pk;
                pk.x = f2bu(av[p].x); pk.y = f2bu(av[p].y);
                pk.z = f2bu(av[p].z); pk.w = f2bu(av[p].w);
                *(ushort4*)(&Af[(arow[p] * 64 + nx * 8 + sgg[p]) * 8 + shalf[p]]) = pk;
            }
        }
        __syncthreads();
    }

    // ---- LN stats: 16-lane group reduce ----
#pragma unroll
    for (int p = 0; p < 2; ++p) {
        s1[p] += __shfl_xor(s1[p], 1); s2[p] += __shfl_xor(s2[p], 1);
        s1[p] += __shfl_xor(s1[p], 2); s2[p] += __shfl_xor(s2[p], 2);
        s1[p] += __shfl_xor(s1[p], 4); s2[p] += __shfl_xor(s2[p], 4);
        s1[p] += __shfl_xor(s1[p], 8); s2[p] += __shfl_xor(s2[p], 8);
    }
    if ((t & 15) == 0) {
#pragma unroll
        for (int p = 0; p < 2; ++p) {
            float mu = s1[p] * (1.0f / H2);
            float rstd = rsqrtf(s2[p] * (1.0f / H2) - mu * mu + 1e-5f);
            MU[arow[p]] = mu; RS[arow[p]] = rstd;
        }
    }

    // ---- epilogue A: +bias; k/q/val via LDS (alias Bs); coalesced dumps ----
    u16* Ks = &Bs_[0][0];                       // 64x64 = 4096 u16
    u16* Qs = &Bs_[0][4096];                    // 64x64 = 4096 u16
    u16* Vs = &Bs_[1][0];                       // 64x72 = 4608 u16 (pad 72)
    int rq = q16 * 4;
#pragma unroll
    for (int j = 0; j < 6; ++j) {
        int n = wn + j * 16 + l15;
        float bias = kqvb[n];
#pragma unroll
        for (int rr = 0; rr < 4; ++rr) {
            int m = wm + rq + rr;
            u16 hv = f2bu(acc[j][rr] + bias);
            if (n < 64)       Ks[m * 64 + n] = hv;
            else if (n < 128) Qs[m * 64 + (n - 64)] = hv;
            else              Vs[(n - 128) * 72 + m] = hv;
        }
    }
    __syncthreads();                            // also publishes MU/RS
    {
        size_t base = (size_t)R0 * 64 + t * 8;
        *(uint4*)(kb + base) = *(const uint4*)(Ks + t * 8);
        *(uint4*)(qb + base) = *(const uint4*)(Qs + t * 8);
        int d = t >> 3, ls = (t & 7) * 8;
        u16* vd = vT + ((size_t)(b * 64 + d)) * 512 + l0 + ls;
        *(uint4*)(vd) = *(const uint4*)(Vs + d * 72 + ls);
    }

    // ---- epilogue B: LN affine from Af -> vnT ----
    {
        int c = t;                              // one column per thread
        float ga = gamma[c], be = beta[c];
        u16* d0 = vnT + ((size_t)(b * H2 + c)) * LL + l0;
        int gbase = c >> 3, coff = c & 7;
#pragma unroll
        for (int lc = 0; lc < 8; ++lc) {
            u16x8 o0;
#pragma unroll
            for (int li = 0; li < 8; ++li) {
                int l = lc * 8 + li;
                u16 w = Af[(l * 64 + (gbase ^ (l & 7))) * 8 + coff];
                o0[li] = f2bu((b2f(w) - MU[l]) * RS[l] * ga + be);
            }
            *(u16x8*)(d0 + lc * 8) = o0;
        }
    }
}

// ========== MFMA flash attention, split-K across 4 waves (unchanged) ==========
#define VLD 136
__global__ __launch_bounds__(256, 4)
void attn_kernel(const u16* __restrict__ qb, const u16* __restrict__ kb,
                 const u16* __restrict__ vT, u16* __restrict__ head) {
    __shared__ u16 Ps[4 * 16 * VLD];
    __shared__ float Osh[4][16 * 65];
    __shared__ float Msh[4][16], Lsh[4][16];
    int b = blockIdx.y, q0 = blockIdx.x * 16;
    int t = threadIdx.x, lane = t & 63, w = t >> 6;
    int l15 = lane & 15, q16 = lane >> 4, q8 = q16 * 8;
    int kc = w * 128;
    const u16* qg = qb + (size_t)b * LL * DA;
    const u16* kg = kb + (size_t)b * LL * DA;
    const u16* vg = vT + (size_t)b * DA * LL;

    bf16x8 aq[2];
#pragma unroll
    for (int s = 0; s < 2; ++s)
        aq[s] = *(const bf16x8*)(qg + (size_t)(q0 + l15) * DA + s * 32 + q8);

    f32x4 sc[8] = {};
#pragma unroll
    for (int j = 0; j < 8; ++j) {
#pragma unroll
        for (int s = 0; s < 2; ++s) {
            bf16x8 bk = *(const bf16x8*)(kg + (size_t)(kc + j * 16 + l15) * DA + s * 32 + q8);
            sc[j] = __builtin_amdgcn_mfma_f32_16x16x32_bf16(aq[s], bk, sc[j], 0, 0, 0);
        }
    }
    float mx[4], sm[4];
#pragma unroll
    for (int j = 0; j < 8; ++j)
#pragma unroll
        for (int rr = 0; rr < 4; ++rr) sc[j][rr] *= 0.125f;
#pragma unroll
    for (int rr = 0; rr < 4; ++rr) {
        float m0 = sc[0][rr];
#pragma unroll
        for (int j = 1; j < 8; ++j) m0 = fmaxf(m0, sc[j][rr]);
        m0 = fmaxf(m0, __shfl_xor(m0, 1));
        m0 = fmaxf(m0, __shfl_xor(m0, 2));
        m0 = fmaxf(m0, __shfl_xor(m0, 4));
        m0 = fmaxf(m0, __shfl_xor(m0, 8));
        mx[rr] = m0;
    }
#pragma unroll
    for (int j = 0; j < 8; ++j)
#pragma unroll
        for (int rr = 0; rr < 4; ++rr) sc[j][rr] = __expf(sc[j][rr] - mx[rr]);
#pragma unroll
    for (int rr = 0; rr < 4; ++rr) {
        float s0 = sc[0][rr];
#pragma unroll
        for (int j = 1; j < 8; ++j) s0 += sc[j][rr];
        s0 += __shfl_xor(s0, 1);
        s0 += __shfl_xor(s0, 2);
        s0 += __shfl_xor(s0, 4);
        s0 += __shfl_xor(s0, 8);
        sm[rr] = s0;
    }
    u16* Pw = Ps + w * 16 * VLD;
#pragma unroll
    for (int j = 0; j < 8; ++j)
#pragma unroll
        for (int rr = 0; rr < 4; ++rr)
            Pw[(q16 * 4 + rr) * VLD + j * 16 + l15] = f2bu(sc[j][rr]);
    f32x4 o[4] = {};
#pragma unroll
    for (int kt = 0; kt < 4; ++kt) {
        bf16x8 ap = *(const bf16x8*)(Pw + l15 * VLD + kt * 32 + q8);
#pragma unroll
        for (int j = 0; j < 4; ++j) {
            bf16x8 bv = *(const bf16x8*)(vg + (size_t)(j * 16 + l15) * LL + kc + kt * 32 + q8);
            o[j] = __builtin_amdgcn_mfma_f32_16x16x32_bf16(ap, bv, o[j], 0, 0, 0);
        }
    }
#pragma unroll
    for (int j = 0; j < 4; ++j)
#pragma unroll
        for (int rr = 0; rr < 4; ++rr)
            Osh[w][(q16 * 4 + rr) * 65 + j * 16 + l15] = o[j][rr];
    if (l15 == 0) {
#pragma unroll
        for (int rr = 0; rr < 4; ++rr) {
            Msh[w][q16 * 4 + rr] = mx[rr];
            Lsh[w][q16 * 4 + rr] = sm[rr];
        }
    }
    __syncthreads();
    int qq = t >> 4, dg = (t & 15) * 4;
    float m0 = Msh[0][qq], m1 = Msh[1][qq], m2 = Msh[2][qq], m3 = Msh[3][qq];
    float ms = fmaxf(fmaxf(m0, m1), fmaxf(m2, m3));
    float f0 = __expf(m0 - ms), f1 = __expf(m1 - ms), f2 = __expf(m2 - ms), f3 = __expf(m3 - ms);
    float lst = Lsh[0][qq] * f0 + Lsh[1][qq] * f1 + Lsh[2][qq] * f2 + Lsh[3][qq] * f3;
    float inv = 1.0f / lst;
    ushort4 res;
    u16* rp = (u16*)&res;
#pragma unroll
    for (int i = 0; i < 4; ++i) {
        int idx = qq * 65 + dg + i;
        float a = Osh[0][idx] * f0 + Osh[1][idx] * f1 + Osh[2][idx] * f2 + Osh[3][idx] * f3;
        rp[i] = f2bu(a * inv);
    }
    *(ushort4*)(head + (size_t)(b * LL + q0 + qq) * DA + dg) = res;
}

// ========== fused Toeplitz GEMM + proj + bias + gate ==========
__device__ __forceinline__ void mfma_tile64(const u16* As, const u16* Bs,
                                            f32x4 acc[4][4], int wm, int wn,
                                            int l15, int q16) {
    int s7 = l15 & 7;
#pragma unroll
    for (int kk = 0; kk < 2; ++kk) {
        int j0 = kk * 4 + q16;
        bf16x8 a[4], bv[4];
#pragma unroll
        for (int i = 0; i < 4; ++i) {
            int row = wm + i * 16 + l15;
            a[i] = *(const bf16x8*)(As + (row * 8 + (j0 ^ s7)) * 8);
        }
#pragma unroll
        for (int j = 0; j < 4; ++j) {
            int row = wn + j * 16 + l15;
            bv[j] = *(const bf16x8*)(Bs + (row * 8 + (j0 ^ s7)) * 8);
        }
#pragma unroll
        for (int i = 0; i < 4; ++i)
#pragma unroll
            for (int j = 0; j < 4; ++j)
                acc[i][j] = __builtin_amdgcn_mfma_f32_16x16x32_bf16(a[i], bv[j], acc[i][j], 0, 0, 0);
    }
}

__device__ __forceinline__ void stage_pair(const u16* A, const u16* B, int ldk,
                                           int koff, u16* Ad, u16* Bd, int t) {
#pragma unroll
    for (int s = 0; s < 4; ++s) {
        int ci = t + s * 256;
        int grow = ci >> 3, gcol = ((ci & 7) ^ (grow & 7)) << 3;
        async_cp16(A + (size_t)grow * ldk + koff + gcol, Ad + ci * 8);
        async_cp16(B + (size_t)grow * ldk + koff + gcol, Bd + ci * 8);
    }
}

__global__ __launch_bounds__(256, 2)
void mix_kernel(const u16* __restrict__ wt,      // [512 m][512 l]
                const u16* __restrict__ vnT,     // [B][512 c][512 l]
                const u16* __restrict__ headb,   // [B][512 m][64 d]
                const u16* __restrict__ projwT,  // [512 c][64 d]
                const float* __restrict__ x,
                const float* __restrict__ tbias,
                const float* __restrict__ projb,
                float* __restrict__ out) {
    __shared__ u16 SMEM[4][128 * 64];            // 64 KiB total (2 blk/CU)
    u16* As0 = SMEM[0]; u16* As1 = SMEM[1];
    u16* Bs0 = SMEM[2]; u16* Bs1 = SMEM[3];
    int lid = blockIdx.x;
    int p8 = lid & 7, rest = lid >> 3;
    int mi = rest & 3, pair = (rest >> 2) * 8 + p8;   // pair in [0,128)
    int b = pair >> 2, m0 = mi * 128, c0 = (pair & 3) * 128;
    int t = threadIdx.x, lane = t & 63, wid = t >> 6;
    int wm = (wid >> 1) * 64, wn = (wid & 1) * 64;
    int l15 = lane & 15, q16 = lane >> 4;
    f32x4 acc[4][4] = {};
    const u16* Ag = wt + (size_t)m0 * 512;
    const u16* Bg = vnT + ((size_t)b * H2 + c0) * 512;
    const u16* Hg = headb + ((size_t)b * LL + m0) * DA;
    const u16* Pg = projwT + (size_t)c0 * DA;

    // prologue: stage tile 0 (Toeplitz k0=0) into buf 0
    stage_pair(Ag, Bg, 512, 0, As0, Bs0, t);
    __syncthreads();                             // drains DMA

    // 9-tile pipeline: 8 Toeplitz K-slabs + proj as tile 8; stage-next ∥ MFMA-current
    for (int it = 0; it < 9; ++it) {
        int nx = it + 1;
        if (nx < 8)
            stage_pair(Ag, Bg, 512, nx * 64, (nx & 1) ? As1 : As0,
                       (nx & 1) ? Bs1 : Bs0, t);
        else if (nx == 8)
            stage_pair(Hg, Pg, 64, 0, As0, Bs0, t);
        mfma_tile64((it & 1) ? As1 : As0, (it & 1) ? Bs1 : Bs0,
                    acc, wm, wn, l15, q16);
        __syncthreads();                         // next-buf ready; cur buf released
    }

    // ---- epilogue: acc -> LDS, then streaming float4 gate pass ----
    float* Acc = (float*)&SMEM[0][0];            // 128x128 fp32 = 64 KiB exact
    int rq = q16 * 4;
#pragma unroll
    for (int i = 0; i < 4; ++i)
#pragma unroll
        for (int j = 0; j < 4; ++j)
#pragma unroll
            for (int rr = 0; rr < 4; ++rr)
                Acc[(wm + i * 16 + rq + rr) * 128 + (wn + j * 16 + l15)] = acc[i][j][rr];
    __syncthreads();
    {
        int cq = (t & 31) * 4, rg = (t >> 5) * 16;
        float4 pj = *(const float4*)(projb + c0 + cq);
#pragma unroll
        for (int rr3 = 0; rr3 < 16; ++rr3) {
            int mrow = rg + rr3;
            int m = m0 + mrow;
            float tb = tbias[m];
            float4 a4 = *(const float4*)(Acc + mrow * 128 + cq);
            float4 xv = *(const float4*)(x + ((size_t)b * LL + m) * HH + c0 + cq);
            float4 o;
            o.x = xv.x * (a4.x + tb + pj.x);
            o.y = xv.y * (a4.y + tb + pj.y);
            o.z = xv.z * (a4.z + tb + pj.z);
            o.w = xv.w * (a4.w + tb + pj.w);
            *(float4*)(out + ((size_t)b * LL + m) * H2 + c0 + cq) = o;
        }
    }
}

extern "C" void kernel_launch(void* const* d_in, const int* in_sizes, int n_in,
                              void* d_out, int out_size, void* d_ws, size_t ws_size,
                              hipStream_t stream) {
    (void)in_sizes; (void)n_in; (void)out_size; (void)ws_size;
    const float* x     = (const float*)d_in[0];
    const float* gamma = (const float*)d_in[1];
    const float* beta  = (const float*)d_in[2];
    const float* wv    = (const float*)d_in[3];
    const float* tb    = (const float*)d_in[4];
    const float* kqvw  = (const float*)d_in[5];
    const float* kqvb  = (const float*)d_in[6];
    const float* projw = (const float*)d_in[7];
    const float* projb = (const float*)d_in[8];
    float* out = (float*)d_out;

    u16* vnT_bf  = (u16*)d_ws;                          // 16 MB
    u16* qb      = vnT_bf + (size_t)NB * LL * H2;       // 2 MB
    u16* kb      = qb + (size_t)NB * LL * DA;           // 2 MB
    u16* vTb     = kb + (size_t)NB * LL * DA;           // 2 MB
    u16* head_bf = vTb + (size_t)NB * LL * DA;          // 2 MB
    u16* wt_bf   = head_bf + (size_t)NB * LL * DA;      // 512 KB
    u16* kqvwT   = wt_bf + 512 * 512;                   // 192 KB
    u16* projwT  = kqvwT + 192 * 512;                   // 64 KB

    prep_kernel <<<1536, 256, 0, stream>>>(wv, kqvw, projw, wt_bf, kqvwT, projwT);
    v_kernel    <<<256, 512, 0, stream>>>(x, kqvwT, kqvb, gamma, beta,
                                          vnT_bf, qb, kb, vTb);
    attn_kernel <<<dim3(32, NB), 256, 0, stream>>>(qb, kb, vTb, head_bf);
    mix_kernel  <<<512, 256, 0, stream>>>(wt_bf, vnT_bf, head_bf, projwT,
                                          x, tb, projb, out);
}